// Round 1
// 659.192 us; speedup vs baseline: 1.0938x; 1.0938x over previous
//
#include <hip/hip_runtime.h>
#include <cstdint>
#include <cmath>

typedef unsigned short u16;
typedef unsigned int   u32;

typedef __bf16 bx8 __attribute__((ext_vector_type(8)));
typedef float  fx4 __attribute__((ext_vector_type(4)));

#define H_  16
#define DH_ 64
// 0.125 (attn scale) * log2(e), folded into stored Q
#define QSCALE 0.18033688011112042f

// ---------- scalar bf16 helpers (raw-bit, RNE) ----------
__device__ __forceinline__ float bf2f(u16 h){ return __uint_as_float(((u32)h) << 16); }
__device__ __forceinline__ u16 f2bf(float f){
  u32 u = __float_as_uint(f);
  u32 r = (u + 0x7FFFu + ((u >> 16) & 1u)) >> 16;
  return (u16)r;
}

// packed f32x2 -> bf16x2 (RNE), single instruction
__device__ __forceinline__ u32 pk_bf16(float a, float b){
  u32 r;
  asm("v_cvt_pk_bf16_f32 %0, %1, %2" : "=v"(r) : "v"(a), "v"(b));
  return r;
}

// dual-dtype element read: f32!=0 -> fp32 array, else bf16 array (element index)
__device__ __forceinline__ float ldv(const void* p, size_t i, int f32){
  return f32 ? ((const float*)p)[i] : bf2f(((const u16*)p)[i]);
}

// async global->LDS, 16B per lane; LDS dest = wave-uniform base + lane*16
__device__ __forceinline__ void gld16(const void* g, void* l){
  __builtin_amdgcn_global_load_lds((const __attribute__((address_space(1))) u32*)g,
                                   (__attribute__((address_space(3))) u32*)l,
                                   16, 0, 0);
}

// UniformAffineQuantizer fake-quant (zp=128, 8-bit)
__device__ __forceinline__ float fq_val(float v, float delta){
  float xi = rintf(v / delta) + 128.0f;
  xi = fminf(fmaxf(xi, 0.0f), 255.0f);
  return (xi - 128.0f) * delta;
}

// fast gelu (tanh form, branchless)
__device__ __forceinline__ float gelu_f(float x){
  float x3 = x * x * x;
  float z = 0.7978845608028654f * x + 0.035677408136300125f * x3;
  float u = __expf(-2.0f * z);
  float t = 1.0f - 2.0f * u / (1.0f + u);
  return 0.5f * x * (1.0f + t);
}

// ---------- input dtype detection ----------
__global__ void detect_k(const u32* __restrict__ x, int* __restrict__ flag){
  __shared__ int cnt;
  if (threadIdx.x == 0) cnt = 0;
  __syncthreads();
  u32 w = x[threadIdx.x];
  int e = (w >> 7) & 0xFF;
  if (e >= 100 && e <= 140) atomicAdd(&cnt, 1);
  __syncthreads();
  if (threadIdx.x == 0) *flag = (cnt < 192) ? 1 : 0;   // 1 == fp32 inputs
}

// ---------- canonicalize a small tensor to bf16 ----------
__global__ __launch_bounds__(256) void cvt_k(const void* __restrict__ in, u16* __restrict__ out,
                                             int n, const int* __restrict__ flagp){
  int f32 = *flagp;
  int i = blockIdx.x * 256 + threadIdx.x;
  if (i < n) out[i] = f32 ? f2bf(((const float*)in)[i]) : ((const u16*)in)[i];
}

// ---------- batched 1024x1024 weight transpose: out[z][n][r] = in_z[r][n] ----------
__global__ __launch_bounds__(256) void tr8_k(
    const void* s0, const void* s1, const void* s2, const void* s3,
    const void* s4, const void* s5, const void* s6, const void* s7,
    u16* __restrict__ out, const int* __restrict__ flagp){
  __shared__ u16 t[32][33];
  int f32 = *flagp;
  int z = blockIdx.z;
  const void* in = z==0?s0:z==1?s1:z==2?s2:z==3?s3:z==4?s4:z==5?s5:z==6?s6:s7;
  u16* o = out + ((size_t)z << 20);
  int n0 = blockIdx.x << 5, r0 = blockIdx.y << 5;
  int tx = threadIdx.x & 31, ty = threadIdx.x >> 5;
  #pragma unroll
  for (int i = 0; i < 4; i++)
    t[ty + i*8][tx] = f2bf(ldv(in, (size_t)(r0 + ty + i*8) * 1024 + n0 + tx, f32));
  __syncthreads();
  #pragma unroll
  for (int i = 0; i < 4; i++)
    o[(size_t)(n0 + ty + i*8) * 1024 + r0 + tx] = t[tx][ty + i*8];
}

// ---------- generic transpose: out[n*Rout + r] = in[r*C + n] ----------
__global__ __launch_bounds__(256) void tr_k(const void* __restrict__ in, u16* __restrict__ out,
                                            int Rout, int C, const int* __restrict__ flagp){
  __shared__ u16 t[32][33];
  int f32 = *flagp;
  int n0 = blockIdx.x << 5, r0 = blockIdx.y << 5;
  int tx = threadIdx.x & 31, ty = threadIdx.x >> 5;
  #pragma unroll
  for (int i = 0; i < 4; i++)
    t[ty + i*8][tx] = f2bf(ldv(in, (size_t)(r0 + ty + i*8) * C + n0 + tx, f32));
  __syncthreads();
  #pragma unroll
  for (int i = 0; i < 4; i++)
    out[(size_t)(n0 + ty + i*8) * Rout + r0 + tx] = t[tx][ty + i*8];
}

// ---------- LayerNorm: (dual or bf16) in -> bf16 out, row = 1024 ----------
__global__ __launch_bounds__(256) void ln_k(const void* __restrict__ x,
    const void* __restrict__ gam, const void* __restrict__ bet, u16* __restrict__ out,
    const int* __restrict__ flagp, int xdual){
  __shared__ float sb[8];
  const int f32 = *flagp;
  const int f32x = xdual ? f32 : 0;
  const int row = blockIdx.x, t = threadIdx.x;
  float v0, v1, v2, v3;
  if (f32x){
    float4 xv = *(const float4*)((const float*)x + (size_t)row * 1024 + t * 4);
    v0 = xv.x; v1 = xv.y; v2 = xv.z; v3 = xv.w;
  } else {
    ushort4 xv = *(const ushort4*)((const u16*)x + (size_t)row * 1024 + t * 4);
    v0 = bf2f(xv.x); v1 = bf2f(xv.y); v2 = bf2f(xv.z); v3 = bf2f(xv.w);
  }
  float s = v0 + v1 + v2 + v3;
  #pragma unroll
  for (int mk = 32; mk; mk >>= 1) s += __shfl_xor(s, mk);
  if ((t & 63) == 0) sb[t >> 6] = s;
  __syncthreads();
  float mu = (sb[0] + sb[1] + sb[2] + sb[3]) * 0.0009765625f;
  float d0 = v0 - mu, d1 = v1 - mu, d2 = v2 - mu, d3 = v3 - mu;
  float ss = d0*d0 + d1*d1 + d2*d2 + d3*d3;
  #pragma unroll
  for (int mk = 32; mk; mk >>= 1) ss += __shfl_xor(ss, mk);
  if ((t & 63) == 0) sb[4 + (t >> 6)] = ss;
  __syncthreads();
  float var = (sb[4] + sb[5] + sb[6] + sb[7]) * 0.0009765625f;
  float rs = rsqrtf(var + 1e-5f);
  int c = t * 4;
  u16 o0 = f2bf(d0 * rs * ldv(gam, c+0, f32) + ldv(bet, c+0, f32));
  u16 o1 = f2bf(d1 * rs * ldv(gam, c+1, f32) + ldv(bet, c+1, f32));
  u16 o2 = f2bf(d2 * rs * ldv(gam, c+2, f32) + ldv(bet, c+2, f32));
  u16 o3 = f2bf(d3 * rs * ldv(gam, c+3, f32) + ldv(bet, c+3, f32));
  uint2 ov; ov.x = (u32)o0 | ((u32)o1 << 16); ov.y = (u32)o2 | ((u32)o3 << 16);
  *(uint2*)(out + (size_t)row * 1024 + c) = ov;
}

// ---------- multi-region fq projection GEMM ----------
// 512 threads / 8 waves; wave computes 32x64 of a 128x128 tile (32 AGPR acc)
__global__ __launch_bounds__(512)
void gemm_mr(const u16* __restrict__ A, const u16* __restrict__ BT,
             u16* __restrict__ P0, u16* __restrict__ P1, u16* __restrict__ P2,
             const void* D0, const void* D1, const void* D2,
             float sc0, float sc1, float sc2,
             int md0, int md1, int md2,
             const int* __restrict__ flagp,
             int M, int K, int rpb, int npad)
{
  __shared__ u16 As[2][128 * 32];
  __shared__ u16 Bs[2][128 * 32];
  const int tid = threadIdx.x;
  const int l = tid & 63, w = tid >> 6;        // 8 waves
  const int lr = l & 15, lq = l >> 4;
  const int m0 = blockIdx.y * 128, n0 = blockIdx.x * 128;
  const int wrow = (w & 3) * 32, wcol = (w >> 2) * 64;

  fx4 acc[2][4];
  #pragma unroll
  for (int i = 0; i < 2; i++)
    #pragma unroll
    for (int j = 0; j < 4; j++){ fx4 z = {0.f,0.f,0.f,0.f}; acc[i][j] = z; }

  const int r0 = tid >> 2, p0 = tid & 3;
  const int c0 = p0 ^ (r0 & 3);
  int am0 = m0 + r0; if (am0 > M - 1) am0 = M - 1;
  const u16* gA = A  + (size_t)am0 * K + c0 * 8;
  const u16* gB = BT + (size_t)(n0 + r0) * K + c0 * 8;
  const int lo = w * 512;                      // wave-uniform LDS elem base

  const int nk = K >> 5;
  gld16(gA, &As[0][lo]);
  gld16(gB, &Bs[0][lo]);

  for (int kt = 0; kt < nk; ++kt){
    __syncthreads();
    const int cur = kt & 1;
    if (kt + 1 < nk){
      const int nb = cur ^ 1;
      const int ko = (kt + 1) << 5;
      gld16(gA + ko, &As[nb][lo]);
      gld16(gB + ko, &Bs[nb][lo]);
    }
    bx8 aF[2], bF[4];
    #pragma unroll
    for (int i = 0; i < 2; i++){
      int row = wrow + i * 16 + lr;
      aF[i] = *(const bx8*)&As[cur][row * 32 + (lq ^ (row & 3)) * 8];
    }
    #pragma unroll
    for (int j = 0; j < 4; j++){
      int row = wcol + j * 16 + lr;
      bF[j] = *(const bx8*)&Bs[cur][row * 32 + (lq ^ (row & 3)) * 8];
    }
    #pragma unroll
    for (int i = 0; i < 2; i++)
      #pragma unroll
      for (int j = 0; j < 4; j++)
        acc[i][j] = __builtin_amdgcn_mfma_f32_16x16x32_bf16(aF[i], bF[j], acc[i][j], 0, 0, 0);
  }

  const int f32 = *flagp;
  const int reg = n0 >> 10;
  const int cbase = n0 & 1023;
  u16* P = reg == 0 ? P0 : (reg == 1 ? P1 : P2);
  const void* D = reg == 0 ? D0 : (reg == 1 ? D1 : D2);
  const float sc = reg == 0 ? sc0 : (reg == 1 ? sc1 : sc2);
  const int md = reg == 0 ? md0 : (reg == 1 ? md1 : md2);
  const float delta = ldv(D, 0, f32);

  #pragma unroll
  for (int i = 0; i < 2; i++)
    #pragma unroll
    for (int j = 0; j < 4; j++)
      #pragma unroll
      for (int rr = 0; rr < 4; rr++){
        int gm = m0 + wrow + i * 16 + lq * 4 + rr;
        int col = cbase + wcol + j * 16 + lr;
        if (gm < M){
          float v = fq_val(acc[i][j][rr], delta) * sc;
          if (md == 0){
            P[(size_t)gm * 1024 + col] = f2bf(v);
          } else {
            int bb = gm / rpb; int jj = gm - bb * rpb;
            int hh = col >> 6, dh = col & 63;
            P[(size_t)((bb * H_ + hh) * DH_ + dh) * npad + jj] = f2bf(v);
          }
        }
      }
}

// ---------- 64x128-tile GEMM (N=1024 shapes, DOUBLE-BUFFERED, 256 thr) ----------
// MODE 0: fq(acc)*sc -> bf16 Co ; MODE 5: acc+bias+res -> bf16 ; MODE 7: final dual store
template<int MODE>
__global__ __launch_bounds__(256)
void gemm64(const u16* __restrict__ A, const u16* __restrict__ BT,
            void* __restrict__ Co, const void* __restrict__ res,
            const void* __restrict__ bias, const void* __restrict__ dptr, float sc,
            const int* __restrict__ flagp, int res_dual,
            int M, int K)
{
  __shared__ u16 As[2][64 * 32];
  __shared__ u16 Bs[2][128 * 32];
  const int tid = threadIdx.x;
  const int l = tid & 63, w = tid >> 6;
  const int lr = l & 15, lq = l >> 4;
  const int m0 = blockIdx.y * 64, n0 = blockIdx.x * 128;
  const int wrow = (w >> 1) * 32, wcol = (w & 1) * 64;

  fx4 acc[2][4];
  #pragma unroll
  for (int i = 0; i < 2; i++)
    #pragma unroll
    for (int j = 0; j < 4; j++){ fx4 z = {0.f,0.f,0.f,0.f}; acc[i][j] = z; }

  const int r0 = tid >> 2, p0 = tid & 3;
  const int c0 = p0 ^ (r0 & 3);
  const int r1 = r0 + 64;
  int am0 = m0 + r0; if (am0 > M - 1) am0 = M - 1;
  const u16* gA0 = A  + (size_t)am0 * K + c0 * 8;
  const u16* gB0 = BT + (size_t)(n0 + r0) * K + c0 * 8;
  const u16* gB1 = BT + (size_t)(n0 + r1) * K + c0 * 8;
  const int lo0 = (w * 64) * 8, lo1 = (256 + w * 64) * 8;

  const int nk = K >> 5;
  gld16(gA0, &As[0][lo0]);
  gld16(gB0, &Bs[0][lo0]);
  gld16(gB1, &Bs[0][lo1]);

  for (int kt = 0; kt < nk; ++kt){
    __syncthreads();
    const int cur = kt & 1;
    if (kt + 1 < nk){
      const int nb = cur ^ 1;
      const int ko = (kt + 1) << 5;
      gld16(gA0 + ko, &As[nb][lo0]);
      gld16(gB0 + ko, &Bs[nb][lo0]);
      gld16(gB1 + ko, &Bs[nb][lo1]);
    }
    bx8 aF[2], bF[4];
    #pragma unroll
    for (int i = 0; i < 2; i++){
      int row = wrow + i * 16 + lr;
      aF[i] = *(const bx8*)&As[cur][row * 32 + (lq ^ (row & 3)) * 8];
    }
    #pragma unroll
    for (int j = 0; j < 4; j++){
      int row = wcol + j * 16 + lr;
      bF[j] = *(const bx8*)&Bs[cur][row * 32 + (lq ^ (row & 3)) * 8];
    }
    #pragma unroll
    for (int i = 0; i < 2; i++)
      #pragma unroll
      for (int j = 0; j < 4; j++)
        acc[i][j] = __builtin_amdgcn_mfma_f32_16x16x32_bf16(aF[i], bF[j], acc[i][j], 0, 0, 0);
  }

  const int f32 = *flagp;
  float delta = 1.f;
  if (MODE == 0) delta = ldv(dptr, 0, f32);

  #pragma unroll
  for (int i = 0; i < 2; i++)
    #pragma unroll
    for (int j = 0; j < 4; j++)
      #pragma unroll
      for (int rr = 0; rr < 4; rr++){
        int gm = m0 + wrow + i * 16 + lq * 4 + rr;
        int gn = n0 + wcol + j * 16 + lr;
        if (gm < M){
          float v = acc[i][j][rr];
          size_t idx = (size_t)gm * 1024 + gn;
          if (MODE == 0){
            ((u16*)Co)[idx] = f2bf(fq_val(v, delta) * sc);
          } else if (MODE == 5){
            float r = res_dual ? ldv(res, idx, f32) : bf2f(((const u16*)res)[idx]);
            ((u16*)Co)[idx] = f2bf(v + ldv(bias, gn, f32) + r);
          } else {
            float o = v + ldv(bias, gn, f32) + bf2f(((const u16*)res)[idx]);
            if (f32) ((float*)Co)[idx] = o;
            else     ((u16*)Co)[idx]  = f2bf(o);
          }
        }
      }
}

// ---------- fused FF1 + GEGLU GEMM ----------
__global__ __launch_bounds__(512)
void gemm_glu(const u16* __restrict__ A, const u16* __restrict__ WT,
              u16* __restrict__ GE, const void* __restrict__ bias,
              const int* __restrict__ flagp, int M, int K)
{
  __shared__ u16 As[2][128 * 32];
  __shared__ u16 Ba[2][128 * 32];
  __shared__ u16 Bg[2][128 * 32];
  const int tid = threadIdx.x;
  const int l = tid & 63, w = tid >> 6;        // 8 waves
  const int lr = l & 15, lq = l >> 4;
  const int m0 = blockIdx.y * 128, n0 = blockIdx.x * 128;
  const int wrow = (w & 3) * 32, wcol = (w >> 2) * 64;

  fx4 accA[2][4], accG[2][4];
  #pragma unroll
  for (int i = 0; i < 2; i++)
    #pragma unroll
    for (int j = 0; j < 4; j++){
      fx4 z = {0.f,0.f,0.f,0.f}; accA[i][j] = z; accG[i][j] = z;
    }

  const int r0 = tid >> 2, p0 = tid & 3;
  const int c0 = p0 ^ (r0 & 3);
  int am0 = m0 + r0; if (am0 > M - 1) am0 = M - 1;
  const u16* gA  = A  + (size_t)am0 * K + c0 * 8;
  const u16* gBa = WT + (size_t)(n0 + r0) * K + c0 * 8;
  const u16* gBg = WT + (size_t)(4096 + n0 + r0) * K + c0 * 8;
  const int lo = w * 512;

  const int nk = K >> 5;
  gld16(gA,  &As[0][lo]);
  gld16(gBa, &Ba[0][lo]);
  gld16(gBg, &Bg[0][lo]);

  for (int kt = 0; kt < nk; ++kt){
    __syncthreads();
    const int cur = kt & 1;
    if (kt + 1 < nk){
      const int nb = cur ^ 1;
      const int ko = (kt + 1) << 5;
      gld16(gA + ko,  &As[nb][lo]);
      gld16(gBa + ko, &Ba[nb][lo]);
      gld16(gBg + ko, &Bg[nb][lo]);
    }
    bx8 aF[2], bFa[4], bFg[4];
    #pragma unroll
    for (int i = 0; i < 2; i++){
      int row = wrow + i * 16 + lr;
      aF[i] = *(const bx8*)&As[cur][row * 32 + (lq ^ (row & 3)) * 8];
    }
    #pragma unroll
    for (int j = 0; j < 4; j++){
      int row = wcol + j * 16 + lr;
      bFa[j] = *(const bx8*)&Ba[cur][row * 32 + (lq ^ (row & 3)) * 8];
      bFg[j] = *(const bx8*)&Bg[cur][row * 32 + (lq ^ (row & 3)) * 8];
    }
    #pragma unroll
    for (int i = 0; i < 2; i++)
      #pragma unroll
      for (int j = 0; j < 4; j++){
        accA[i][j] = __builtin_amdgcn_mfma_f32_16x16x32_bf16(aF[i], bFa[j], accA[i][j], 0, 0, 0);
        accG[i][j] = __builtin_amdgcn_mfma_f32_16x16x32_bf16(aF[i], bFg[j], accG[i][j], 0, 0, 0);
      }
  }

  const int f32 = *flagp;

  #pragma unroll
  for (int i = 0; i < 2; i++)
    #pragma unroll
    for (int j = 0; j < 4; j++)
      #pragma unroll
      for (int rr = 0; rr < 4; rr++){
        int gm = m0 + wrow + i * 16 + lq * 4 + rr;
        int gn = n0 + wcol + j * 16 + lr;
        float va = accA[i][j][rr] + ldv(bias, gn, f32);
        float vg = accG[i][j][rr] + ldv(bias, 4096 + gn, f32);
        GE[(size_t)gm * 4096 + gn] = f2bf(va * gelu_f(vg));
      }
}

// ---------- fused quantized attention, two-pass, Q-tile 128, J-tile 128, 512 thr ----------
// Swapped-operand QK^T: mfma(K, Q) => D rows = k (lane lq*4+rr, 4 consecutive),
// D cols = q (lane lr). Quantized P packed via v_cvt_pk_bf16_f32, one b64 LDS
// write per 4 values. P stores xi (integer counts, exact in bf16); *dw folded
// into the output epilogue. No clamps needed: pass1/pass2 MFMA+exp2 are
// bit-identical, so s >= max term  =>  rint(e*cr) in [0,255] provably.
// Staging: global_load_lds w/ XOR-swizzled per-lane global source; K dbuf.
// LDS: Ks[2](16K) + Vs(16K) + Ps(32K) = 80 KiB -> exactly 2 blocks/CU (16 waves).
__global__ __launch_bounds__(512, 4) void attn_k(
    const u16* __restrict__ Qf, const u16* __restrict__ Kf,
    const u16* __restrict__ VT, u16* __restrict__ AO,
    const void* __restrict__ dwp, const int* __restrict__ flagp,
    int Nq, int Lk, int Lpad)
{
  __shared__ u16 lds[40960];                 // 81920 B
  u16* const KB0 = lds;                      // [128][64]
  u16* const KB1 = lds + 8192;               // [128][64]
  u16* const Vs  = lds + 16384;              // [64][128]
  u16* const Ps  = lds + 24576;              // [128][128]

  const int tid = threadIdx.x, l = tid & 63, w = tid >> 6;   // 8 waves
  const int lr = l & 15, lq = l >> 4, m = lr & 7;
  const int q0 = blockIdx.x << 7;
  const int b = blockIdx.y >> 4, hh = blockIdx.y & 15;
  const int wq = w << 4;
  const float dw = ldv(dwp, 0, *flagp);

  // Q fragment (2nd operand): lane lr = q row, elems lq*8 .. +8
  const u16* qp = Qf + ((size_t)(b * Nq + q0 + wq + lr) << 10) + (hh << 6) + (lq << 3);
  bx8 aQ0 = *(const bx8*)(qp);
  bx8 aQ1 = *(const bx8*)(qp + 32);

  // staging lane constants
  const int krl = (w << 3) + (l >> 3), kcl = l & 7;     // K: 64 rows/call, 8 chunks/row
  const int vrl = (w << 2) + (l >> 4), vcl = l & 15;    // V: 32 rows/call, 16 chunks/row

  auto stageK = [&](u16* dst, int j0){
    #pragma unroll
    for (int t = 0; t < 2; ++t){
      int r = krl + (t << 6);
      int jr = j0 + r; if (jr > Lk - 1) jr = Lk - 1;
      int c = kcl ^ (r & 7);
      gld16(Kf + ((size_t)(b * Lk + jr) << 10) + (hh << 6) + (c << 3),
            dst + (w << 9) + (t << 12));
    }
  };
  auto stageV = [&](int j0){
    #pragma unroll
    for (int t = 0; t < 2; ++t){
      int dh = vrl + (t << 5);
      int c = vcl ^ (dh & 7);
      gld16(VT + (size_t)((((b << 4) + hh) << 6) + dh) * Lpad + j0 + (c << 3),
            Vs + (w << 9) + (t << 12));
    }
  };

  const int ntiles = (Lk + 127) >> 7;
  const int ch0 = ((lq ^ m) << 3), ch1 = (((lq + 4) ^ m) << 3);

  // -------- pass 1: row sums of exp2 --------
  float sa0 = 0.f, sa1 = 0.f, sa2 = 0.f, sa3 = 0.f;
  stageK(KB0, 0);
  for (int jt = 0; jt < ntiles; ++jt){
    __syncthreads();
    const u16* Kc = (jt & 1) ? KB1 : KB0;
    if (jt + 1 < ntiles) stageK((jt & 1) ? KB0 : KB1, (jt + 1) << 7);
    const int j0 = jt << 7;
    const bool full = (j0 + 128 <= Lk);
    #pragma unroll
    for (int j = 0; j < 8; ++j){
      const int ro = ((j << 4) + lr) << 6;
      bx8 k0 = *(const bx8*)&Kc[ro + ch0];
      bx8 k1 = *(const bx8*)&Kc[ro + ch1];
      fx4 sv = {0.f,0.f,0.f,0.f};
      sv = __builtin_amdgcn_mfma_f32_16x16x32_bf16(k0, aQ0, sv, 0, 0, 0);
      sv = __builtin_amdgcn_mfma_f32_16x16x32_bf16(k1, aQ1, sv, 0, 0, 0);
      if (full){
        sa0 += exp2f(sv[0]); sa1 += exp2f(sv[1]);
        sa2 += exp2f(sv[2]); sa3 += exp2f(sv[3]);
      } else {
        const int kb = j0 + (j << 4) + (lq << 2);
        sa0 += (kb + 0 < Lk) ? exp2f(sv[0]) : 0.f;
        sa1 += (kb + 1 < Lk) ? exp2f(sv[1]) : 0.f;
        sa2 += (kb + 2 < Lk) ? exp2f(sv[2]) : 0.f;
        sa3 += (kb + 3 < Lk) ? exp2f(sv[3]) : 0.f;
      }
    }
  }
  __syncthreads();
  float s = (sa0 + sa1) + (sa2 + sa3);
  s += __shfl_xor(s, 16);
  s += __shfl_xor(s, 32);
  const float cr = (1.0f / dw) / s;          // e*cr in [0,255] by construction

  // -------- pass 2: quantize P and accumulate P@V^T --------
  fx4 oacc[4];
  #pragma unroll
  for (int dj = 0; dj < 4; ++dj){ fx4 z = {0.f,0.f,0.f,0.f}; oacc[dj] = z; }

  const int qloc = wq + lr;
  const int pw = (qloc << 7) + (lq << 2);    // Ps write base (u16)

  stageK(KB0, 0);
  for (int jt = 0; jt < ntiles; ++jt){
    __syncthreads();
    const int j0 = jt << 7;
    stageV(j0);
    if (jt + 1 < ntiles) stageK((jt & 1) ? KB0 : KB1, j0 + 128);
    const u16* Kc = (jt & 1) ? KB1 : KB0;
    const bool full = (j0 + 128 <= Lk);
    #pragma unroll
    for (int j = 0; j < 8; ++j){
      const int ro = ((j << 4) + lr) << 6;
      bx8 k0 = *(const bx8*)&Kc[ro + ch0];
      bx8 k1 = *(const bx8*)&Kc[ro + ch1];
      fx4 sv = {0.f,0.f,0.f,0.f};
      sv = __builtin_amdgcn_mfma_f32_16x16x32_bf16(k0, aQ0, sv, 0, 0, 0);
      sv = __builtin_amdgcn_mfma_f32_16x16x32_bf16(k1, aQ1, sv, 0, 0, 0);
      float x0, x1, x2, x3;
      if (full){
        x0 = rintf(exp2f(sv[0]) * cr);
        x1 = rintf(exp2f(sv[1]) * cr);
        x2 = rintf(exp2f(sv[2]) * cr);
        x3 = rintf(exp2f(sv[3]) * cr);
      } else {
        const int kb = j0 + (j << 4) + (lq << 2);
        x0 = (kb + 0 < Lk) ? rintf(exp2f(sv[0]) * cr) : 0.f;
        x1 = (kb + 1 < Lk) ? rintf(exp2f(sv[1]) * cr) : 0.f;
        x2 = (kb + 2 < Lk) ? rintf(exp2f(sv[2]) * cr) : 0.f;
        x3 = (kb + 3 < Lk) ? rintf(exp2f(sv[3]) * cr) : 0.f;
      }
      uint2 pp; pp.x = pk_bf16(x0, x1); pp.y = pk_bf16(x2, x3);
      *(uint2*)&Ps[pw + ((j ^ m) << 4)] = pp;
    }
    __syncthreads();
    #pragma unroll
    for (int kk = 0; kk < 4; ++kk){
      bx8 aP = *(const bx8*)&Ps[(qloc << 7) + ((((kk << 3) + (lq << 1)) ^ (m << 2)) << 2)];
      #pragma unroll
      for (int dj = 0; dj < 4; ++dj){
        bx8 bV = *(const bx8*)&Vs[((((dj << 4) + lr)) << 7) + ((((kk << 2) + lq) ^ m) << 3)];
        oacc[dj] = __builtin_amdgcn_mfma_f32_16x16x32_bf16(aP, bV, oacc[dj], 0, 0, 0);
      }
    }
  }

  const size_t ob = ((size_t)(b * Nq + q0 + wq + (lq << 2)) << 10) + (hh << 6) + lr;
  #pragma unroll
  for (int dj = 0; dj < 4; ++dj)
    #pragma unroll
    for (int rr = 0; rr < 4; ++rr)
      AO[ob + ((size_t)rr << 10) + (dj << 4)] = f2bf(oacc[dj][rr] * dw);
}

// =====================================================================

extern "C" void kernel_launch(void* const* d_in, const int* in_sizes, int n_in,
                              void* d_out, int out_size, void* d_ws, size_t ws_size,
                              hipStream_t stream)
{
  const void* X    = d_in[0];
  const void* CTX  = d_in[1];
  const void* LN1G = d_in[2];
  const void* LN1B = d_in[3];
  const void* LN2G = d_in[4];
  const void* LN2B = d_in[5];
  const void* LN3G = d_in[6];
  const void* LN3B = d_in[7];
  const void* W1Q  = d_in[8];
  const void* W1K  = d_in[9];
  const void* W1V  = d_in[10];
  const void* W1O  = d_in[11];
  const void* B1O  = d_in[12];
  const void* W2Q  = d_in[13];
  const void* W2K  = d_in[14];
  const void* W2V  = d_in[15];
  const void* W2O  = d_in[16];
  const void* B2O  = d_in[17];
  const void* FW1  = d_in[18];
  const void* FB1  = d_in[19];
  const void* FW2  = d_in[20];
  const void* FB2  = d_in[21];
  const void* DQ1  = d_in[22];
  const void* DK1  = d_in[23];
  const void* DV1  = d_in[24];
  const void* DW1  = d_in[25];
  const void* DQ2  = d_in[26];
  const void* DK2  = d_in[27];
  const void* DV2  = d_in[28];
  const void* DW2  = d_in[29];

  // workspace layout (~66 MiB):
  char* ws = (char*)d_ws;
  u16* wslot = (u16*)(ws + (0ull  << 20)); // 16 MiB: 8 attn W^T -> FW1^T -> FW2^T
  u16* xs    = (u16*)(ws + (16ull << 20)); //  8 MiB bf16 residual stream
  u16* h     = (u16*)(ws + (24ull << 20)); //  8 MiB LN output / attn output
  u16* bufA  = (u16*)(ws + (32ull << 20)); //  8 MiB qf
  u16* bufB  = (u16*)(ws + (40ull << 20)); //  8 MiB kf
  u16* bufC  = (u16*)(ws + (48ull << 20)); //  8 MiB vt
  u16* ge    = bufA;                       // 32 MiB alias (32..64): qkv dead by FF stage
  u16* ctxc  = (u16*)(ws + (64ull << 20)); // ~0.3 MiB canonical bf16 context
  int* flag  = (int*)(ws + (65ull << 20)); // dtype flag

  const dim3 G8x64(8, 64), GAT(16, 32);
  const int NCTX = 154 * 1024;
  const size_t MB2 = 1048576;   // elements per 1024x1024 weight

  detect_k<<<1, 256, 0, stream>>>((const u32*)X, flag);
  cvt_k<<<(NCTX + 255) / 256, 256, 0, stream>>>(CTX, ctxc, NCTX, flag);
  tr8_k<<<dim3(32, 32, 8), 256, 0, stream>>>(W1Q, W1K, W1V, W1O, W2Q, W2K, W2V, W2O,
                                             wslot, flag);

  // ---- self-attention:  x = attn1(ln1(x)) + x ----
  ln_k<<<4096, 256, 0, stream>>>(X, LN1G, LN1B, h, flag, 1);
  gemm_mr<<<dim3(24, 32), 512, 0, stream>>>(h, wslot,
      bufA, bufB, bufC, DQ1, DK1, DV1, QSCALE, 1.f, 1.f, 0, 0, 1,
      flag, 4096, 1024, 2048, 2048);
  attn_k<<<GAT, 512, 0, stream>>>(bufA, bufB, bufC, h, DW1, flag, 2048, 2048, 2048);
  gemm64<5><<<G8x64, 256, 0, stream>>>(h, wslot + 3 * MB2, xs, X, B1O, nullptr, 1.f,
                                       flag, 1, 4096, 1024);

  // ---- cross-attention:  x = attn2(ln2(x), ctx) + x ----
  ln_k<<<4096, 256, 0, stream>>>(xs, LN2G, LN2B, h, flag, 0);
  gemm64<0><<<G8x64, 256, 0, stream>>>(h, wslot + 4 * MB2, bufA, nullptr, nullptr, DQ2,
                                       QSCALE, flag, 0, 4096, 1024);
  gemm_mr<<<dim3(16, 2), 512, 0, stream>>>(ctxc, wslot + 5 * MB2,
      bufB, bufC, nullptr, DK2, DV2, DV2, 1.f, 1.f, 1.f, 0, 1, 1,
      flag, 154, 1024, 77, 128);
  attn_k<<<GAT, 512, 0, stream>>>(bufA, bufB, bufC, h, DW2, flag, 2048, 77, 128);
  gemm64<5><<<G8x64, 256, 0, stream>>>(h, wslot + 7 * MB2, xs, xs, B2O, nullptr, 1.f,
                                       flag, 0, 4096, 1024);

  // ---- GEGLU feed-forward:  x = (a * gelu(g)) @ w2 + b2 + x ----
  ln_k<<<4096, 256, 0, stream>>>(xs, LN3G, LN3B, h, flag, 0);
  tr_k<<<dim3(256, 32), 256, 0, stream>>>(FW1, wslot, 1024, 8192, flag);   // [8192][1024]
  gemm_glu<<<dim3(32, 32), 512, 0, stream>>>(h, wslot, ge, FB1, flag, 4096, 1024);
  tr_k<<<dim3(32, 128), 256, 0, stream>>>(FW2, wslot, 4096, 1024, flag);   // [1024][4096]
  gemm64<7><<<G8x64, 256, 0, stream>>>(ge, wslot, d_out, xs, FB2, nullptr, 1.f,
                                       flag, 0, 4096, 4096);
}

// Round 2
// 651.100 us; speedup vs baseline: 1.1074x; 1.0124x over previous
//
#include <hip/hip_runtime.h>
#include <cstdint>
#include <cmath>

typedef unsigned short u16;
typedef unsigned int   u32;

typedef __bf16 bx8 __attribute__((ext_vector_type(8)));
typedef float  fx4 __attribute__((ext_vector_type(4)));
typedef u32    ux4 __attribute__((ext_vector_type(4)));

#define H_  16
#define DH_ 64
// 0.125 (attn scale) * log2(e), folded into stored Q
#define QSCALE 0.18033688011112042f

#if __has_builtin(__builtin_amdgcn_exp2f)
#define EXP2(x) __builtin_amdgcn_exp2f(x)
#else
#define EXP2(x) exp2f(x)
#endif

// ---------- scalar bf16 helpers (raw-bit, RNE) ----------
__device__ __forceinline__ float bf2f(u16 h){ return __uint_as_float(((u32)h) << 16); }
__device__ __forceinline__ u16 f2bf(float f){
  u32 u = __float_as_uint(f);
  u32 r = (u + 0x7FFFu + ((u >> 16) & 1u)) >> 16;
  return (u16)r;
}

// packed f32x2 -> bf16x2 (RNE), single instruction
__device__ __forceinline__ u32 pk_bf16(float a, float b){
  u32 r;
  asm("v_cvt_pk_bf16_f32 %0, %1, %2" : "=v"(r) : "v"(a), "v"(b));
  return r;
}

union pkc { ux4 u; bx8 v; };

// dual-dtype element read: f32!=0 -> fp32 array, else bf16 array (element index)
__device__ __forceinline__ float ldv(const void* p, size_t i, int f32){
  return f32 ? ((const float*)p)[i] : bf2f(((const u16*)p)[i]);
}

// async global->LDS, 16B per lane; LDS dest = wave-uniform base + lane*16
__device__ __forceinline__ void gld16(const void* g, void* l){
  __builtin_amdgcn_global_load_lds((const __attribute__((address_space(1))) u32*)g,
                                   (__attribute__((address_space(3))) u32*)l,
                                   16, 0, 0);
}

// UniformAffineQuantizer fake-quant (zp=128, 8-bit)
__device__ __forceinline__ float fq_val(float v, float delta){
  float xi = rintf(v / delta) + 128.0f;
  xi = fminf(fmaxf(xi, 0.0f), 255.0f);
  return (xi - 128.0f) * delta;
}

// fast gelu (tanh form, branchless)
__device__ __forceinline__ float gelu_f(float x){
  float x3 = x * x * x;
  float z = 0.7978845608028654f * x + 0.035677408136300125f * x3;
  float u = __expf(-2.0f * z);
  float t = 1.0f - 2.0f * u / (1.0f + u);
  return 0.5f * x * (1.0f + t);
}

// ---------- input dtype detection ----------
__global__ void detect_k(const u32* __restrict__ x, int* __restrict__ flag){
  __shared__ int cnt;
  if (threadIdx.x == 0) cnt = 0;
  __syncthreads();
  u32 w = x[threadIdx.x];
  int e = (w >> 7) & 0xFF;
  if (e >= 100 && e <= 140) atomicAdd(&cnt, 1);
  __syncthreads();
  if (threadIdx.x == 0) *flag = (cnt < 192) ? 1 : 0;   // 1 == fp32 inputs
}

// ---------- canonicalize a small tensor to bf16 ----------
__global__ __launch_bounds__(256) void cvt_k(const void* __restrict__ in, u16* __restrict__ out,
                                             int n, const int* __restrict__ flagp){
  int f32 = *flagp;
  int i = blockIdx.x * 256 + threadIdx.x;
  if (i < n) out[i] = f32 ? f2bf(((const float*)in)[i]) : ((const u16*)in)[i];
}

// ---------- batched 1024x1024 weight transpose: out[z][n][r] = in_z[r][n] ----------
__global__ __launch_bounds__(256) void tr8_k(
    const void* s0, const void* s1, const void* s2, const void* s3,
    const void* s4, const void* s5, const void* s6, const void* s7,
    u16* __restrict__ out, const int* __restrict__ flagp){
  __shared__ u16 t[32][33];
  int f32 = *flagp;
  int z = blockIdx.z;
  const void* in = z==0?s0:z==1?s1:z==2?s2:z==3?s3:z==4?s4:z==5?s5:z==6?s6:s7;
  u16* o = out + ((size_t)z << 20);
  int n0 = blockIdx.x << 5, r0 = blockIdx.y << 5;
  int tx = threadIdx.x & 31, ty = threadIdx.x >> 5;
  #pragma unroll
  for (int i = 0; i < 4; i++)
    t[ty + i*8][tx] = f2bf(ldv(in, (size_t)(r0 + ty + i*8) * 1024 + n0 + tx, f32));
  __syncthreads();
  #pragma unroll
  for (int i = 0; i < 4; i++)
    o[(size_t)(n0 + ty + i*8) * 1024 + r0 + tx] = t[tx][ty + i*8];
}

// ---------- generic transpose: out[n*Rout + r] = in[r*C + n] ----------
__global__ __launch_bounds__(256) void tr_k(const void* __restrict__ in, u16* __restrict__ out,
                                            int Rout, int C, const int* __restrict__ flagp){
  __shared__ u16 t[32][33];
  int f32 = *flagp;
  int n0 = blockIdx.x << 5, r0 = blockIdx.y << 5;
  int tx = threadIdx.x & 31, ty = threadIdx.x >> 5;
  #pragma unroll
  for (int i = 0; i < 4; i++)
    t[ty + i*8][tx] = f2bf(ldv(in, (size_t)(r0 + ty + i*8) * C + n0 + tx, f32));
  __syncthreads();
  #pragma unroll
  for (int i = 0; i < 4; i++)
    out[(size_t)(n0 + ty + i*8) * Rout + r0 + tx] = t[tx][ty + i*8];
}

// ---------- LayerNorm: (dual or bf16) in -> bf16 out, row = 1024 ----------
__global__ __launch_bounds__(256) void ln_k(const void* __restrict__ x,
    const void* __restrict__ gam, const void* __restrict__ bet, u16* __restrict__ out,
    const int* __restrict__ flagp, int xdual){
  __shared__ float sb[8];
  const int f32 = *flagp;
  const int f32x = xdual ? f32 : 0;
  const int row = blockIdx.x, t = threadIdx.x;
  float v0, v1, v2, v3;
  if (f32x){
    float4 xv = *(const float4*)((const float*)x + (size_t)row * 1024 + t * 4);
    v0 = xv.x; v1 = xv.y; v2 = xv.z; v3 = xv.w;
  } else {
    ushort4 xv = *(const ushort4*)((const u16*)x + (size_t)row * 1024 + t * 4);
    v0 = bf2f(xv.x); v1 = bf2f(xv.y); v2 = bf2f(xv.z); v3 = bf2f(xv.w);
  }
  float s = v0 + v1 + v2 + v3;
  #pragma unroll
  for (int mk = 32; mk; mk >>= 1) s += __shfl_xor(s, mk);
  if ((t & 63) == 0) sb[t >> 6] = s;
  __syncthreads();
  float mu = (sb[0] + sb[1] + sb[2] + sb[3]) * 0.0009765625f;
  float d0 = v0 - mu, d1 = v1 - mu, d2 = v2 - mu, d3 = v3 - mu;
  float ss = d0*d0 + d1*d1 + d2*d2 + d3*d3;
  #pragma unroll
  for (int mk = 32; mk; mk >>= 1) ss += __shfl_xor(ss, mk);
  if ((t & 63) == 0) sb[4 + (t >> 6)] = ss;
  __syncthreads();
  float var = (sb[4] + sb[5] + sb[6] + sb[7]) * 0.0009765625f;
  float rs = rsqrtf(var + 1e-5f);
  int c = t * 4;
  u16 o0 = f2bf(d0 * rs * ldv(gam, c+0, f32) + ldv(bet, c+0, f32));
  u16 o1 = f2bf(d1 * rs * ldv(gam, c+1, f32) + ldv(bet, c+1, f32));
  u16 o2 = f2bf(d2 * rs * ldv(gam, c+2, f32) + ldv(bet, c+2, f32));
  u16 o3 = f2bf(d3 * rs * ldv(gam, c+3, f32) + ldv(bet, c+3, f32));
  uint2 ov; ov.x = (u32)o0 | ((u32)o1 << 16); ov.y = (u32)o2 | ((u32)o3 << 16);
  *(uint2*)(out + (size_t)row * 1024 + c) = ov;
}

// ---------- multi-region fq projection GEMM ----------
// 512 threads / 8 waves; wave computes 32x64 of a 128x128 tile (32 AGPR acc)
__global__ __launch_bounds__(512)
void gemm_mr(const u16* __restrict__ A, const u16* __restrict__ BT,
             u16* __restrict__ P0, u16* __restrict__ P1, u16* __restrict__ P2,
             const void* D0, const void* D1, const void* D2,
             float sc0, float sc1, float sc2,
             int md0, int md1, int md2,
             const int* __restrict__ flagp,
             int M, int K, int rpb, int npad)
{
  __shared__ u16 As[2][128 * 32];
  __shared__ u16 Bs[2][128 * 32];
  const int tid = threadIdx.x;
  const int l = tid & 63, w = tid >> 6;        // 8 waves
  const int lr = l & 15, lq = l >> 4;
  const int m0 = blockIdx.y * 128, n0 = blockIdx.x * 128;
  const int wrow = (w & 3) * 32, wcol = (w >> 2) * 64;

  fx4 acc[2][4];
  #pragma unroll
  for (int i = 0; i < 2; i++)
    #pragma unroll
    for (int j = 0; j < 4; j++){ fx4 z = {0.f,0.f,0.f,0.f}; acc[i][j] = z; }

  const int r0 = tid >> 2, p0 = tid & 3;
  const int c0 = p0 ^ (r0 & 3);
  int am0 = m0 + r0; if (am0 > M - 1) am0 = M - 1;
  const u16* gA = A  + (size_t)am0 * K + c0 * 8;
  const u16* gB = BT + (size_t)(n0 + r0) * K + c0 * 8;
  const int lo = w * 512;                      // wave-uniform LDS elem base

  const int nk = K >> 5;
  gld16(gA, &As[0][lo]);
  gld16(gB, &Bs[0][lo]);

  for (int kt = 0; kt < nk; ++kt){
    __syncthreads();
    const int cur = kt & 1;
    if (kt + 1 < nk){
      const int nb = cur ^ 1;
      const int ko = (kt + 1) << 5;
      gld16(gA + ko, &As[nb][lo]);
      gld16(gB + ko, &Bs[nb][lo]);
    }
    bx8 aF[2], bF[4];
    #pragma unroll
    for (int i = 0; i < 2; i++){
      int row = wrow + i * 16 + lr;
      aF[i] = *(const bx8*)&As[cur][row * 32 + (lq ^ (row & 3)) * 8];
    }
    #pragma unroll
    for (int j = 0; j < 4; j++){
      int row = wcol + j * 16 + lr;
      bF[j] = *(const bx8*)&Bs[cur][row * 32 + (lq ^ (row & 3)) * 8];
    }
    #pragma unroll
    for (int i = 0; i < 2; i++)
      #pragma unroll
      for (int j = 0; j < 4; j++)
        acc[i][j] = __builtin_amdgcn_mfma_f32_16x16x32_bf16(aF[i], bF[j], acc[i][j], 0, 0, 0);
  }

  const int f32 = *flagp;
  const int reg = n0 >> 10;
  const int cbase = n0 & 1023;
  u16* P = reg == 0 ? P0 : (reg == 1 ? P1 : P2);
  const void* D = reg == 0 ? D0 : (reg == 1 ? D1 : D2);
  const float sc = reg == 0 ? sc0 : (reg == 1 ? sc1 : sc2);
  const int md = reg == 0 ? md0 : (reg == 1 ? md1 : md2);
  const float delta = ldv(D, 0, f32);

  #pragma unroll
  for (int i = 0; i < 2; i++)
    #pragma unroll
    for (int j = 0; j < 4; j++)
      #pragma unroll
      for (int rr = 0; rr < 4; rr++){
        int gm = m0 + wrow + i * 16 + lq * 4 + rr;
        int col = cbase + wcol + j * 16 + lr;
        if (gm < M){
          float v = fq_val(acc[i][j][rr], delta) * sc;
          if (md == 0){
            P[(size_t)gm * 1024 + col] = f2bf(v);
          } else {
            int bb = gm / rpb; int jj = gm - bb * rpb;
            int hh = col >> 6, dh = col & 63;
            P[(size_t)((bb * H_ + hh) * DH_ + dh) * npad + jj] = f2bf(v);
          }
        }
      }
}

// ---------- 64x128-tile GEMM (N=1024 shapes, DOUBLE-BUFFERED, 256 thr) ----------
// MODE 0: fq(acc)*sc -> bf16 Co ; MODE 5: acc+bias+res -> bf16 ; MODE 7: final dual store
template<int MODE>
__global__ __launch_bounds__(256)
void gemm64(const u16* __restrict__ A, const u16* __restrict__ BT,
            void* __restrict__ Co, const void* __restrict__ res,
            const void* __restrict__ bias, const void* __restrict__ dptr, float sc,
            const int* __restrict__ flagp, int res_dual,
            int M, int K)
{
  __shared__ u16 As[2][64 * 32];
  __shared__ u16 Bs[2][128 * 32];
  const int tid = threadIdx.x;
  const int l = tid & 63, w = tid >> 6;
  const int lr = l & 15, lq = l >> 4;
  const int m0 = blockIdx.y * 64, n0 = blockIdx.x * 128;
  const int wrow = (w >> 1) * 32, wcol = (w & 1) * 64;

  fx4 acc[2][4];
  #pragma unroll
  for (int i = 0; i < 2; i++)
    #pragma unroll
    for (int j = 0; j < 4; j++){ fx4 z = {0.f,0.f,0.f,0.f}; acc[i][j] = z; }

  const int r0 = tid >> 2, p0 = tid & 3;
  const int c0 = p0 ^ (r0 & 3);
  const int r1 = r0 + 64;
  int am0 = m0 + r0; if (am0 > M - 1) am0 = M - 1;
  const u16* gA0 = A  + (size_t)am0 * K + c0 * 8;
  const u16* gB0 = BT + (size_t)(n0 + r0) * K + c0 * 8;
  const u16* gB1 = BT + (size_t)(n0 + r1) * K + c0 * 8;
  const int lo0 = (w * 64) * 8, lo1 = (256 + w * 64) * 8;

  const int nk = K >> 5;
  gld16(gA0, &As[0][lo0]);
  gld16(gB0, &Bs[0][lo0]);
  gld16(gB1, &Bs[0][lo1]);

  for (int kt = 0; kt < nk; ++kt){
    __syncthreads();
    const int cur = kt & 1;
    if (kt + 1 < nk){
      const int nb = cur ^ 1;
      const int ko = (kt + 1) << 5;
      gld16(gA0 + ko, &As[nb][lo0]);
      gld16(gB0 + ko, &Bs[nb][lo0]);
      gld16(gB1 + ko, &Bs[nb][lo1]);
    }
    bx8 aF[2], bF[4];
    #pragma unroll
    for (int i = 0; i < 2; i++){
      int row = wrow + i * 16 + lr;
      aF[i] = *(const bx8*)&As[cur][row * 32 + (lq ^ (row & 3)) * 8];
    }
    #pragma unroll
    for (int j = 0; j < 4; j++){
      int row = wcol + j * 16 + lr;
      bF[j] = *(const bx8*)&Bs[cur][row * 32 + (lq ^ (row & 3)) * 8];
    }
    #pragma unroll
    for (int i = 0; i < 2; i++)
      #pragma unroll
      for (int j = 0; j < 4; j++)
        acc[i][j] = __builtin_amdgcn_mfma_f32_16x16x32_bf16(aF[i], bF[j], acc[i][j], 0, 0, 0);
  }

  const int f32 = *flagp;
  float delta = 1.f;
  if (MODE == 0) delta = ldv(dptr, 0, f32);

  #pragma unroll
  for (int i = 0; i < 2; i++)
    #pragma unroll
    for (int j = 0; j < 4; j++)
      #pragma unroll
      for (int rr = 0; rr < 4; rr++){
        int gm = m0 + wrow + i * 16 + lq * 4 + rr;
        int gn = n0 + wcol + j * 16 + lr;
        if (gm < M){
          float v = acc[i][j][rr];
          size_t idx = (size_t)gm * 1024 + gn;
          if (MODE == 0){
            ((u16*)Co)[idx] = f2bf(fq_val(v, delta) * sc);
          } else if (MODE == 5){
            float r = res_dual ? ldv(res, idx, f32) : bf2f(((const u16*)res)[idx]);
            ((u16*)Co)[idx] = f2bf(v + ldv(bias, gn, f32) + r);
          } else {
            float o = v + ldv(bias, gn, f32) + bf2f(((const u16*)res)[idx]);
            if (f32) ((float*)Co)[idx] = o;
            else     ((u16*)Co)[idx]  = f2bf(o);
          }
        }
      }
}

// ---------- fused FF1 + GEGLU GEMM ----------
__global__ __launch_bounds__(512)
void gemm_glu(const u16* __restrict__ A, const u16* __restrict__ WT,
              u16* __restrict__ GE, const void* __restrict__ bias,
              const int* __restrict__ flagp, int M, int K)
{
  __shared__ u16 As[2][128 * 32];
  __shared__ u16 Ba[2][128 * 32];
  __shared__ u16 Bg[2][128 * 32];
  const int tid = threadIdx.x;
  const int l = tid & 63, w = tid >> 6;        // 8 waves
  const int lr = l & 15, lq = l >> 4;
  const int m0 = blockIdx.y * 128, n0 = blockIdx.x * 128;
  const int wrow = (w & 3) * 32, wcol = (w >> 2) * 64;

  fx4 accA[2][4], accG[2][4];
  #pragma unroll
  for (int i = 0; i < 2; i++)
    #pragma unroll
    for (int j = 0; j < 4; j++){
      fx4 z = {0.f,0.f,0.f,0.f}; accA[i][j] = z; accG[i][j] = z;
    }

  const int r0 = tid >> 2, p0 = tid & 3;
  const int c0 = p0 ^ (r0 & 3);
  int am0 = m0 + r0; if (am0 > M - 1) am0 = M - 1;
  const u16* gA  = A  + (size_t)am0 * K + c0 * 8;
  const u16* gBa = WT + (size_t)(n0 + r0) * K + c0 * 8;
  const u16* gBg = WT + (size_t)(4096 + n0 + r0) * K + c0 * 8;
  const int lo = w * 512;

  const int nk = K >> 5;
  gld16(gA,  &As[0][lo]);
  gld16(gBa, &Ba[0][lo]);
  gld16(gBg, &Bg[0][lo]);

  for (int kt = 0; kt < nk; ++kt){
    __syncthreads();
    const int cur = kt & 1;
    if (kt + 1 < nk){
      const int nb = cur ^ 1;
      const int ko = (kt + 1) << 5;
      gld16(gA + ko,  &As[nb][lo]);
      gld16(gBa + ko, &Ba[nb][lo]);
      gld16(gBg + ko, &Bg[nb][lo]);
    }
    bx8 aF[2], bFa[4], bFg[4];
    #pragma unroll
    for (int i = 0; i < 2; i++){
      int row = wrow + i * 16 + lr;
      aF[i] = *(const bx8*)&As[cur][row * 32 + (lq ^ (row & 3)) * 8];
    }
    #pragma unroll
    for (int j = 0; j < 4; j++){
      int row = wcol + j * 16 + lr;
      bFa[j] = *(const bx8*)&Ba[cur][row * 32 + (lq ^ (row & 3)) * 8];
      bFg[j] = *(const bx8*)&Bg[cur][row * 32 + (lq ^ (row & 3)) * 8];
    }
    #pragma unroll
    for (int i = 0; i < 2; i++)
      #pragma unroll
      for (int j = 0; j < 4; j++){
        accA[i][j] = __builtin_amdgcn_mfma_f32_16x16x32_bf16(aF[i], bFa[j], accA[i][j], 0, 0, 0);
        accG[i][j] = __builtin_amdgcn_mfma_f32_16x16x32_bf16(aF[i], bFg[j], accG[i][j], 0, 0, 0);
      }
  }

  const int f32 = *flagp;

  #pragma unroll
  for (int i = 0; i < 2; i++)
    #pragma unroll
    for (int j = 0; j < 4; j++)
      #pragma unroll
      for (int rr = 0; rr < 4; rr++){
        int gm = m0 + wrow + i * 16 + lq * 4 + rr;
        int gn = n0 + wcol + j * 16 + lr;
        float va = accA[i][j][rr] + ldv(bias, gn, f32);
        float vg = accG[i][j][rr] + ldv(bias, 4096 + gn, f32);
        GE[(size_t)gm * 4096 + gn] = f2bf(va * gelu_f(vg));
      }
}

// ---------- fused quantized attention, two-pass, Q-tile 128, 256 thr / 4 waves ----------
// Each wave owns 32 q-rows (2 groups of 16) -> every K/V ds_read_b128 feeds 2 MFMAs.
// Swapped QK^T (mfma(K,Q)): lane (lq,lr) holds sv for k=16j+4lq+rr, q=lr.
// P never touches LDS: xi packed with v_cvt_pk_bf16_f32, then
// v_permlane32_swap_b32 + v_permlane16_swap_b32 rearrange the j-pair (2t,2t+1)
// dwords into the exact MFMA B-fragment P[k=32t+8lq+e][q=lr]:
//   swap32(A,B): A'={A.r0,A.r1,B.r0,B.r1}, B'={A.r2,A.r3,B.r2,B.r3}
//   swap16(X,Y): X'={X.r0,Y.r0,X.r2,Y.r2}, Y'={X.r1,Y.r1,X.r3,Y.r3}
//   (A0,B0)->(R0,R2), (A1,B1)->(R1,R3); fragment = {R0,R1,R2,R3}.
// K and V both double-buffered -> ONE barrier per tile. LDS = 64 KiB -> 2 blk/CU.
__global__ __launch_bounds__(256) void attn_k(
    const u16* __restrict__ Qf, const u16* __restrict__ Kf,
    const u16* __restrict__ VT, u16* __restrict__ AO,
    const void* __restrict__ dwp, const int* __restrict__ flagp,
    int Nq, int Lk, int Lpad)
{
  __shared__ u16 lds[32768];                   // 64 KiB
  u16* const KB0_ = lds;                       // [128][64]
  u16* const KB1_ = lds + 8192;
  u16* const VB0_ = lds + 16384;               // [64][128]
  u16* const VB1_ = lds + 24576;

  const int tid = threadIdx.x, l = tid & 63, w = tid >> 6;   // 4 waves
  const int lr = l & 15, lq = l >> 4, m = lr & 7;
  const int q0 = blockIdx.x << 7;
  const int b = blockIdx.y >> 4, hh = blockIdx.y & 15;
  const int wq = w << 5;                       // 32 q per wave
  const float dw = ldv(dwp, 0, *flagp);
  const float rdw = 1.0f / dw;

  // Q fragments (2nd operand): lane lr = q col, elems lq*8..+8 / +32
  bx8 aQ[2][2];
  #pragma unroll
  for (int g = 0; g < 2; ++g){
    const u16* qp = Qf + ((size_t)(b * Nq + q0 + wq + g * 16 + lr) << 10)
                       + (hh << 6) + (lq << 3);
    aQ[g][0] = *(const bx8*)(qp);
    aQ[g][1] = *(const bx8*)(qp + 32);
  }

  // staging lane constants (256 thr, 4 rounds of 4 KB per 16 KB tile)
  const int kr0 = tid >> 3, kc = (tid & 7) ^ (kr0 & 7);      // K: row, swz chunk
  const int vd0 = tid >> 4, vc = (tid & 15) ^ (vd0 & 7);     // V: d-row, swz chunk
  const int ldsb = w << 9;                                   // wave slot base (elems)

  auto stageK = [&](u16* dst, int j0){
    #pragma unroll
    for (int q = 0; q < 4; ++q){
      int r = kr0 + (q << 5);
      int jr = j0 + r; if (jr > Lk - 1) jr = Lk - 1;
      gld16(Kf + ((size_t)(b * Lk + jr) << 10) + (hh << 6) + (kc << 3),
            dst + (q << 11) + ldsb);
    }
  };
  auto stageV = [&](u16* dst, int j0){
    #pragma unroll
    for (int q = 0; q < 4; ++q){
      int d = vd0 + (q << 4);
      gld16(VT + ((size_t)(((b << 4) + hh) << 6) + d) * Lpad + j0 + (vc << 3),
            dst + (q << 11) + ldsb);
    }
  };

  const int ntiles = (Lk + 127) >> 7;
  const int ch0 = ((lq ^ m) << 3), ch1 = (((lq + 4) ^ m) << 3);

  // -------- pass 1: row sums of exp2 --------
  float sa[2][4];
  #pragma unroll
  for (int g = 0; g < 2; ++g)
    #pragma unroll
    for (int rr = 0; rr < 4; ++rr) sa[g][rr] = 0.f;

  stageK(KB0_, 0);
  for (int jt = 0; jt < ntiles; ++jt){
    __syncthreads();
    const int cur = jt & 1;
    if (jt + 1 < ntiles) stageK(cur ? KB0_ : KB1_, (jt + 1) << 7);
    const u16* Kc = cur ? KB1_ : KB0_;
    const int j0 = jt << 7;
    const bool full = (j0 + 128 <= Lk);
    #pragma unroll
    for (int j = 0; j < 8; ++j){
      const int ro = ((j << 4) + lr) << 6;
      bx8 k0 = *(const bx8*)&Kc[ro + ch0];
      bx8 k1 = *(const bx8*)&Kc[ro + ch1];
      #pragma unroll
      for (int g = 0; g < 2; ++g){
        fx4 sv = {0.f,0.f,0.f,0.f};
        sv = __builtin_amdgcn_mfma_f32_16x16x32_bf16(k0, aQ[g][0], sv, 0, 0, 0);
        sv = __builtin_amdgcn_mfma_f32_16x16x32_bf16(k1, aQ[g][1], sv, 0, 0, 0);
        if (full){
          sa[g][0] += EXP2(sv[0]); sa[g][1] += EXP2(sv[1]);
          sa[g][2] += EXP2(sv[2]); sa[g][3] += EXP2(sv[3]);
        } else {
          const int kb = j0 + (j << 4) + (lq << 2);
          sa[g][0] += (kb + 0 < Lk) ? EXP2(sv[0]) : 0.f;
          sa[g][1] += (kb + 1 < Lk) ? EXP2(sv[1]) : 0.f;
          sa[g][2] += (kb + 2 < Lk) ? EXP2(sv[2]) : 0.f;
          sa[g][3] += (kb + 3 < Lk) ? EXP2(sv[3]) : 0.f;
        }
      }
    }
  }

  float cr[2];
  #pragma unroll
  for (int g = 0; g < 2; ++g){
    float s = (sa[g][0] + sa[g][1]) + (sa[g][2] + sa[g][3]);
    s += __shfl_xor(s, 16);
    s += __shfl_xor(s, 32);
    cr[g] = rdw / s;                 // e*cr in [0,255] by construction
  }

  // -------- pass 2: quantize P in-register and accumulate V^T @ P --------
  fx4 oacc[2][4];
  #pragma unroll
  for (int g = 0; g < 2; ++g)
    #pragma unroll
    for (int dj = 0; dj < 4; ++dj){ fx4 z = {0.f,0.f,0.f,0.f}; oacc[g][dj] = z; }

  __syncthreads();                   // all waves done with pass-1 LDS
  stageK(KB0_, 0);
  stageV(VB0_, 0);
  for (int jt = 0; jt < ntiles; ++jt){
    __syncthreads();
    const int cur = jt & 1;
    const int j0 = jt << 7;
    if (jt + 1 < ntiles){
      stageK(cur ? KB0_ : KB1_, j0 + 128);
      stageV(cur ? VB0_ : VB1_, j0 + 128);
    }
    const u16* Kc = cur ? KB1_ : KB0_;
    const u16* Vc = cur ? VB1_ : VB0_;
    const bool full = (j0 + 128 <= Lk);
    #pragma unroll
    for (int t = 0; t < 4; ++t){
      u32 pA0[2], pA1[2], pB0[2], pB1[2];
      #pragma unroll
      for (int jj = 0; jj < 2; ++jj){
        const int j = (t << 1) + jj;
        const int ro = ((j << 4) + lr) << 6;
        bx8 k0 = *(const bx8*)&Kc[ro + ch0];
        bx8 k1 = *(const bx8*)&Kc[ro + ch1];
        #pragma unroll
        for (int g = 0; g < 2; ++g){
          fx4 sv = {0.f,0.f,0.f,0.f};
          sv = __builtin_amdgcn_mfma_f32_16x16x32_bf16(k0, aQ[g][0], sv, 0, 0, 0);
          sv = __builtin_amdgcn_mfma_f32_16x16x32_bf16(k1, aQ[g][1], sv, 0, 0, 0);
          float x0, x1, x2, x3;
          if (full){
            x0 = rintf(EXP2(sv[0]) * cr[g]);
            x1 = rintf(EXP2(sv[1]) * cr[g]);
            x2 = rintf(EXP2(sv[2]) * cr[g]);
            x3 = rintf(EXP2(sv[3]) * cr[g]);
          } else {
            const int kb = j0 + (j << 4) + (lq << 2);
            x0 = (kb + 0 < Lk) ? rintf(EXP2(sv[0]) * cr[g]) : 0.f;
            x1 = (kb + 1 < Lk) ? rintf(EXP2(sv[1]) * cr[g]) : 0.f;
            x2 = (kb + 2 < Lk) ? rintf(EXP2(sv[2]) * cr[g]) : 0.f;
            x3 = (kb + 3 < Lk) ? rintf(EXP2(sv[3]) * cr[g]) : 0.f;
          }
          u32 plo = pk_bf16(x0, x1), phi = pk_bf16(x2, x3);
          if (jj == 0){ pA0[g] = plo; pA1[g] = phi; }
          else        { pB0[g] = plo; pB1[g] = phi; }
        }
      }
      bx8 pa[2];
      #pragma unroll
      for (int g = 0; g < 2; ++g){
        u32 r0 = pA0[g], r2 = pB0[g], r1 = pA1[g], r3 = pB1[g];
        asm volatile("v_permlane32_swap_b32 %0, %1" : "+v"(r0), "+v"(r2));
        asm volatile("v_permlane16_swap_b32 %0, %1" : "+v"(r0), "+v"(r2));
        asm volatile("v_permlane32_swap_b32 %0, %1" : "+v"(r1), "+v"(r3));
        asm volatile("v_permlane16_swap_b32 %0, %1" : "+v"(r1), "+v"(r3));
        pkc pc; ux4 uu = {r0, r1, r2, r3}; pc.u = uu; pa[g] = pc.v;
      }
      #pragma unroll
      for (int dj = 0; dj < 4; ++dj){
        bx8 bV = *(const bx8*)&Vc[(((dj << 4) + lr) << 7) + ((((t << 2) + lq) ^ m) << 3)];
        oacc[0][dj] = __builtin_amdgcn_mfma_f32_16x16x32_bf16(bV, pa[0], oacc[0][dj], 0, 0, 0);
        oacc[1][dj] = __builtin_amdgcn_mfma_f32_16x16x32_bf16(bV, pa[1], oacc[1][dj], 0, 0, 0);
      }
    }
  }

  // output: rows = d (lq*4+rr within dj*16), cols = q (lr); 8-B packed stores
  #pragma unroll
  for (int g = 0; g < 2; ++g){
    const size_t ob = ((size_t)(b * Nq + q0 + wq + g * 16 + lr) << 10)
                    + (hh << 6) + (lq << 2);
    #pragma unroll
    for (int dj = 0; dj < 4; ++dj){
      uint2 ov;
      ov.x = (u32)f2bf(oacc[g][dj][0] * dw) | ((u32)f2bf(oacc[g][dj][1] * dw) << 16);
      ov.y = (u32)f2bf(oacc[g][dj][2] * dw) | ((u32)f2bf(oacc[g][dj][3] * dw) << 16);
      *(uint2*)(AO + ob + (dj << 4)) = ov;
    }
  }
}

// =====================================================================

extern "C" void kernel_launch(void* const* d_in, const int* in_sizes, int n_in,
                              void* d_out, int out_size, void* d_ws, size_t ws_size,
                              hipStream_t stream)
{
  const void* X    = d_in[0];
  const void* CTX  = d_in[1];
  const void* LN1G = d_in[2];
  const void* LN1B = d_in[3];
  const void* LN2G = d_in[4];
  const void* LN2B = d_in[5];
  const void* LN3G = d_in[6];
  const void* LN3B = d_in[7];
  const void* W1Q  = d_in[8];
  const void* W1K  = d_in[9];
  const void* W1V  = d_in[10];
  const void* W1O  = d_in[11];
  const void* B1O  = d_in[12];
  const void* W2Q  = d_in[13];
  const void* W2K  = d_in[14];
  const void* W2V  = d_in[15];
  const void* W2O  = d_in[16];
  const void* B2O  = d_in[17];
  const void* FW1  = d_in[18];
  const void* FB1  = d_in[19];
  const void* FW2  = d_in[20];
  const void* FB2  = d_in[21];
  const void* DQ1  = d_in[22];
  const void* DK1  = d_in[23];
  const void* DV1  = d_in[24];
  const void* DW1  = d_in[25];
  const void* DQ2  = d_in[26];
  const void* DK2  = d_in[27];
  const void* DV2  = d_in[28];
  const void* DW2  = d_in[29];

  // workspace layout (~66 MiB):
  char* ws = (char*)d_ws;
  u16* wslot = (u16*)(ws + (0ull  << 20)); // 16 MiB: 8 attn W^T -> FW1^T -> FW2^T
  u16* xs    = (u16*)(ws + (16ull << 20)); //  8 MiB bf16 residual stream
  u16* h     = (u16*)(ws + (24ull << 20)); //  8 MiB LN output / attn output
  u16* bufA  = (u16*)(ws + (32ull << 20)); //  8 MiB qf
  u16* bufB  = (u16*)(ws + (40ull << 20)); //  8 MiB kf
  u16* bufC  = (u16*)(ws + (48ull << 20)); //  8 MiB vt
  u16* ge    = bufA;                       // 32 MiB alias (32..64): qkv dead by FF stage
  u16* ctxc  = (u16*)(ws + (64ull << 20)); // ~0.3 MiB canonical bf16 context
  int* flag  = (int*)(ws + (65ull << 20)); // dtype flag

  const dim3 G8x64(8, 64), GAT(16, 32);
  const int NCTX = 154 * 1024;
  const size_t MB2 = 1048576;   // elements per 1024x1024 weight

  detect_k<<<1, 256, 0, stream>>>((const u32*)X, flag);
  cvt_k<<<(NCTX + 255) / 256, 256, 0, stream>>>(CTX, ctxc, NCTX, flag);
  tr8_k<<<dim3(32, 32, 8), 256, 0, stream>>>(W1Q, W1K, W1V, W1O, W2Q, W2K, W2V, W2O,
                                             wslot, flag);

  // ---- self-attention:  x = attn1(ln1(x)) + x ----
  ln_k<<<4096, 256, 0, stream>>>(X, LN1G, LN1B, h, flag, 1);
  gemm_mr<<<dim3(24, 32), 512, 0, stream>>>(h, wslot,
      bufA, bufB, bufC, DQ1, DK1, DV1, QSCALE, 1.f, 1.f, 0, 0, 1,
      flag, 4096, 1024, 2048, 2048);
  attn_k<<<GAT, 256, 0, stream>>>(bufA, bufB, bufC, h, DW1, flag, 2048, 2048, 2048);
  gemm64<5><<<G8x64, 256, 0, stream>>>(h, wslot + 3 * MB2, xs, X, B1O, nullptr, 1.f,
                                       flag, 1, 4096, 1024);

  // ---- cross-attention:  x = attn2(ln2(x), ctx) + x ----
  ln_k<<<4096, 256, 0, stream>>>(xs, LN2G, LN2B, h, flag, 0);
  gemm64<0><<<G8x64, 256, 0, stream>>>(h, wslot + 4 * MB2, bufA, nullptr, nullptr, DQ2,
                                       QSCALE, flag, 0, 4096, 1024);
  gemm_mr<<<dim3(16, 2), 512, 0, stream>>>(ctxc, wslot + 5 * MB2,
      bufB, bufC, nullptr, DK2, DV2, DV2, 1.f, 1.f, 1.f, 0, 1, 1,
      flag, 154, 1024, 77, 128);
  attn_k<<<GAT, 256, 0, stream>>>(bufA, bufB, bufC, h, DW2, flag, 2048, 77, 128);
  gemm64<5><<<G8x64, 256, 0, stream>>>(h, wslot + 7 * MB2, xs, xs, B2O, nullptr, 1.f,
                                       flag, 0, 4096, 1024);

  // ---- GEGLU feed-forward:  x = (a * gelu(g)) @ w2 + b2 + x ----
  ln_k<<<4096, 256, 0, stream>>>(xs, LN3G, LN3B, h, flag, 0);
  tr_k<<<dim3(256, 32), 256, 0, stream>>>(FW1, wslot, 1024, 8192, flag);   // [8192][1024]
  gemm_glu<<<dim3(32, 32), 512, 0, stream>>>(h, wslot, ge, FB1, flag, 4096, 1024);
  tr_k<<<dim3(32, 128), 256, 0, stream>>>(FW2, wslot, 4096, 1024, flag);   // [1024][4096]
  gemm64<7><<<G8x64, 256, 0, stream>>>(ge, wslot, d_out, xs, FB2, nullptr, 1.f,
                                       flag, 0, 4096, 4096);
}